// Round 2
// baseline (372.570 us; speedup 1.0000x reference)
//
#include <hip/hip_runtime.h>
#include <stdint.h>

#define S_LEN 2048
#define BATCH 2
#define EMB   1024
#define NHEAD 16
#define HDIM  64

typedef __bf16 bf8 __attribute__((ext_vector_type(8)));
typedef float  f32x4 __attribute__((ext_vector_type(4)));

__device__ __forceinline__ unsigned short f2bf(float f) {
    unsigned u = __builtin_bit_cast(unsigned, f);
    u += 0x7fffu + ((u >> 16) & 1u);          // round-to-nearest-even
    return (unsigned short)(u >> 16);
}
__device__ __forceinline__ float bf2f(unsigned short h) {
    unsigned u = ((unsigned)h) << 16;
    return __builtin_bit_cast(float, u);
}

__device__ __forceinline__ void gl_lds16(const unsigned short* g, unsigned short* l) {
    __builtin_amdgcn_global_load_lds(
        (__attribute__((address_space(1))) void*)(void*)g,
        (__attribute__((address_space(3))) void*)(void*)l, 16, 0, 0);
}

// ---------------- rope tables: cos/sin [S][64] fp32 ----------------
__global__ void k_tables(float* __restrict__ cosT, float* __restrict__ sinT) {
    int idx = blockIdx.x * 256 + threadIdx.x;   // 2048*64 = 131072
    int s = idx >> 6, d = idx & 63, j = d & 31;
    float inv = exp2f(-13.28771237954945f * ((float)j * (1.0f / 32.0f))); // 10000^(-j/32)
    float ang = (float)s * inv;
    cosT[idx] = cosf(ang);
    sinT[idx] = sinf(ang);
}

// ---------------- cast query [S,B,E] f32 -> xb [B,S,E] bf16 ----------------
__global__ void k_cast_x(const float* __restrict__ x, unsigned short* __restrict__ xb) {
    int id = blockIdx.x * 256 + threadIdx.x;    // 1048576 (4 elems each)
    int b = id >> 19, rem = id & 524287;
    int s = rem >> 8, e4 = (rem & 255) << 2;
    float4 v = *(const float4*)&x[((size_t)(s * BATCH + b)) * EMB + e4];
    ushort4 o;
    o.x = f2bf(v.x); o.y = f2bf(v.y); o.z = f2bf(v.z); o.w = f2bf(v.w);
    *(ushort4*)&xb[((size_t)(b * S_LEN + s)) * EMB + e4] = o;
}

// ---------------- generic f32 -> bf16 cast (weights) ----------------
__global__ void k_cast4(const float* __restrict__ a, unsigned short* __restrict__ o, int n4) {
    int id = blockIdx.x * 256 + threadIdx.x;
    if (id < n4) {
        float4 v = *(const float4*)&a[(size_t)id * 4];
        ushort4 u;
        u.x = f2bf(v.x); u.y = f2bf(v.y); u.z = f2bf(v.z); u.w = f2bf(v.w);
        *(ushort4*)&o[(size_t)id * 4] = u;
    }
}

// ---------------- RoPE in-place on [B,S,E] bf16 buffer ----------------
__global__ void k_rope(unsigned short* __restrict__ buf,
                       const float* __restrict__ cosT, const float* __restrict__ sinT) {
    int id = blockIdx.x * 256 + threadIdx.x;    // B*S*H*32 = 2097152
    int d = id & 31;
    int h = (id >> 5) & 15;
    int s = (id >> 9) & 2047;
    int b = id >> 20;
    size_t base = ((size_t)(b * S_LEN + s)) * EMB + h * HDIM + d;
    float x1 = bf2f(buf[base]);
    float x2 = bf2f(buf[base + 32]);
    float c  = cosT[s * 64 + d];
    float sn = sinT[s * 64 + d];
    buf[base]      = f2bf(x1 * c - x2 * sn);
    buf[base + 32] = f2bf(x2 * c + x1 * sn);
}

// ---------------- GEMM: C[M][N] = A[M][K] * B[N][K]^T + bias ----------------
// EPI 0: C row-major [M][N] bf16, bias over cols (q/k projections)
// EPI 1: C row-major [M][N] bf16, bias over rows (vT = W*X^T, bias per f-row)
// EPI 2: fp32 output, bias over cols, rows remapped m=b*2048+s -> s*2+b (d_out)
template<int EPI, typename OutT>
__global__ void __launch_bounds__(256) k_gemm(
    const unsigned short* __restrict__ A,
    const unsigned short* __restrict__ B,
    const float* __restrict__ bias,
    OutT* __restrict__ C,
    int M, int N, int K)
{
    __shared__ __align__(16) unsigned short As[128 * 32];
    __shared__ __align__(16) unsigned short Bs[128 * 32];
    const int tid  = threadIdx.x;
    const int lane = tid & 63;
    const int wid  = tid >> 6;
    const int wm = wid >> 1, wn = wid & 1;
    const int l15 = lane & 15, lh = lane >> 4;
    const int tm0 = blockIdx.y * 128, tn0 = blockIdx.x * 128;

    f32x4 acc[4][4] = {};

    for (int k0 = 0; k0 < K; k0 += 32) {
        __syncthreads();
#pragma unroll
        for (int rnd = 0; rnd < 2; ++rnd) {
            int cbase = wid * 64 + rnd * 256;          // wave-uniform chunk base
            int c = cbase + lane;
            int row = c >> 2, co = (c & 3) * 8;
            gl_lds16(A + (size_t)(tm0 + row) * K + k0 + co, &As[cbase * 8]);
            gl_lds16(B + (size_t)(tn0 + row) * K + k0 + co, &Bs[cbase * 8]);
        }
        __syncthreads();
        bf8 a[4], b[4];
#pragma unroll
        for (int i = 0; i < 4; ++i) {
            a[i] = *(const bf8*)&As[(wm * 64 + i * 16 + l15) * 32 + lh * 8];
            b[i] = *(const bf8*)&Bs[(wn * 64 + i * 16 + l15) * 32 + lh * 8];
        }
#pragma unroll
        for (int i = 0; i < 4; ++i)
#pragma unroll
            for (int j = 0; j < 4; ++j)
                acc[i][j] = __builtin_amdgcn_mfma_f32_16x16x32_bf16(a[i], b[j], acc[i][j], 0, 0, 0);
    }

#pragma unroll
    for (int i = 0; i < 4; ++i) {
        const int rowb = tm0 + wm * 64 + i * 16 + lh * 4;
#pragma unroll
        for (int j = 0; j < 4; ++j) {
            const int col = tn0 + wn * 64 + j * 16 + l15;
#pragma unroll
            for (int r = 0; r < 4; ++r) {
                float v = acc[i][j][r];
                int row = rowb + r;
                if (EPI == 0) {
                    v += bias[col];
                    C[(size_t)row * N + col] = (OutT)f2bf(v);
                } else if (EPI == 1) {
                    v += bias[row];
                    C[(size_t)row * N + col] = (OutT)f2bf(v);
                } else {
                    v += bias[col];
                    int bb = row >> 11, ss = row & 2047;
                    ((float*)C)[(size_t)(ss * BATCH + bb) * N + col] = v;
                }
            }
        }
    }
}

// ---------------- flash attention ----------------
// grid: (S/64, B*H). 4 waves/block, each wave owns 16 q rows.
// qb,kb: [B,S,E] bf16 (rope'd). vT: [E][B*S] bf16 (v transposed, bias included).
// ob: [B,S,E] bf16 attention output.
__global__ void __launch_bounds__(256) k_attn(
    const unsigned short* __restrict__ qb,
    const unsigned short* __restrict__ kb,
    const unsigned short* __restrict__ vT,
    unsigned short* __restrict__ ob)
{
    __shared__ __align__(16) unsigned short P[4][16 * 32];
    const int tid = threadIdx.x, lane = tid & 63, wid = tid >> 6;
    const int l15 = lane & 15, lh = lane >> 4;
    const int bh = blockIdx.y;
    const int b = bh >> 4, h = bh & 15;
    const int q0 = blockIdx.x * 64 + wid * 16;

    const unsigned short* qrow = qb + ((size_t)(b * S_LEN + q0 + l15)) * EMB + h * HDIM;
    bf8 qf0 = *(const bf8*)(qrow + lh * 8);
    bf8 qf1 = *(const bf8*)(qrow + 32 + lh * 8);

    float mrun[4] = {-INFINITY, -INFINITY, -INFINITY, -INFINITY};
    float lrun[4] = {0.f, 0.f, 0.f, 0.f};
    f32x4 oacc[4] = {};

    unsigned short* pl = &P[wid][0];

    for (int j0 = 0; j0 < S_LEN; j0 += 32) {
        f32x4 sc[2];
#pragma unroll
        for (int half = 0; half < 2; ++half) {
            const unsigned short* krow =
                kb + ((size_t)(b * S_LEN + j0 + half * 16 + l15)) * EMB + h * HDIM;
            bf8 kf0 = *(const bf8*)(krow + lh * 8);
            bf8 kf1 = *(const bf8*)(krow + 32 + lh * 8);
            f32x4 t = {};
            t = __builtin_amdgcn_mfma_f32_16x16x32_bf16(qf0, kf0, t, 0, 0, 0);
            t = __builtin_amdgcn_mfma_f32_16x16x32_bf16(qf1, kf1, t, 0, 0, 0);
            sc[half] = t * 0.125f;           // 1/sqrt(64)
        }
        float corr[4], mnew[4];
#pragma unroll
        for (int r = 0; r < 4; ++r) {
            float m = fmaxf(sc[0][r], sc[1][r]);
            m = fmaxf(m, __shfl_xor(m, 1));
            m = fmaxf(m, __shfl_xor(m, 2));
            m = fmaxf(m, __shfl_xor(m, 4));
            m = fmaxf(m, __shfl_xor(m, 8));
            float mn = fmaxf(mrun[r], m);
            corr[r] = expf(mrun[r] - mn);
            mnew[r] = mn;
            mrun[r] = mn;
        }
        float p0[4], p1[4];
#pragma unroll
        for (int r = 0; r < 4; ++r) {
            p0[r] = expf(sc[0][r] - mnew[r]);
            p1[r] = expf(sc[1][r] - mnew[r]);
            float sum = p0[r] + p1[r];
            sum += __shfl_xor(sum, 1);
            sum += __shfl_xor(sum, 2);
            sum += __shfl_xor(sum, 4);
            sum += __shfl_xor(sum, 8);
            lrun[r] = lrun[r] * corr[r] + sum;
#pragma unroll
            for (int dt = 0; dt < 4; ++dt) oacc[dt][r] *= corr[r];
        }
        // transpose P (D-layout -> A-layout) through LDS, bf16
#pragma unroll
        for (int r = 0; r < 4; ++r) {
            pl[(lh * 4 + r) * 32 + l15]      = f2bf(p0[r]);
            pl[(lh * 4 + r) * 32 + 16 + l15] = f2bf(p1[r]);
        }
        bf8 pf = *(const bf8*)&pl[l15 * 32 + lh * 8];
#pragma unroll
        for (int dt = 0; dt < 4; ++dt) {
            const unsigned short* vrow =
                vT + ((size_t)(h * HDIM + dt * 16 + l15)) * (S_LEN * BATCH)
                   + b * S_LEN + j0 + lh * 8;
            bf8 vf = *(const bf8*)vrow;
            oacc[dt] = __builtin_amdgcn_mfma_f32_16x16x32_bf16(pf, vf, oacc[dt], 0, 0, 0);
        }
    }
#pragma unroll
    for (int dt = 0; dt < 4; ++dt)
#pragma unroll
        for (int r = 0; r < 4; ++r) {
            float o = oacc[dt][r] / lrun[r];
            ob[((size_t)(b * S_LEN + q0 + lh * 4 + r)) * EMB + h * HDIM + dt * 16 + l15] = f2bf(o);
        }
}

extern "C" void kernel_launch(void* const* d_in, const int* in_sizes, int n_in,
                              void* d_out, int out_size, void* d_ws, size_t ws_size,
                              hipStream_t stream)
{
    (void)in_sizes; (void)n_in; (void)out_size; (void)ws_size;
    const float* query = (const float*)d_in[0];
    const float* wq = (const float*)d_in[1];
    const float* bq = (const float*)d_in[2];
    const float* wk = (const float*)d_in[3];
    const float* bk = (const float*)d_in[4];
    const float* wv = (const float*)d_in[5];
    const float* bv = (const float*)d_in[6];
    const float* wo = (const float*)d_in[7];
    const float* bo = (const float*)d_in[8];

    char* ws = (char*)d_ws;
    float*          cosT = (float*)(ws + 0);
    float*          sinT = (float*)(ws + (512 << 10));
    unsigned short* xb   = (unsigned short*)(ws + (1  << 20));  // [B,S,E]   8 MB
    unsigned short* wqb  = (unsigned short*)(ws + (9  << 20));  // [E,E]     2 MB
    unsigned short* wkb  = (unsigned short*)(ws + (11 << 20));
    unsigned short* wvb  = (unsigned short*)(ws + (13 << 20));
    unsigned short* wob  = (unsigned short*)(ws + (15 << 20));
    unsigned short* qb   = (unsigned short*)(ws + (17 << 20));  // [B,S,E]
    unsigned short* kb   = (unsigned short*)(ws + (25 << 20));
    unsigned short* vT   = (unsigned short*)(ws + (33 << 20));  // [E][B*S]
    unsigned short* ob   = (unsigned short*)(ws + (41 << 20));  // [B,S,E]

    k_tables<<<512, 256, 0, stream>>>(cosT, sinT);
    k_cast_x<<<4096, 256, 0, stream>>>(query, xb);
    k_cast4<<<1024, 256, 0, stream>>>(wq, wqb, 262144);
    k_cast4<<<1024, 256, 0, stream>>>(wk, wkb, 262144);
    k_cast4<<<1024, 256, 0, stream>>>(wv, wvb, 262144);
    k_cast4<<<1024, 256, 0, stream>>>(wo, wob, 262144);

    dim3 g1(EMB / 128, (S_LEN * BATCH) / 128);   // (8, 32)
    k_gemm<0, unsigned short><<<g1, 256, 0, stream>>>(xb, wqb, bq, qb, 4096, 1024, 1024);
    k_gemm<0, unsigned short><<<g1, 256, 0, stream>>>(xb, wkb, bk, kb, 4096, 1024, 1024);
    dim3 g2((S_LEN * BATCH) / 128, EMB / 128);   // (32, 8)
    k_gemm<1, unsigned short><<<g2, 256, 0, stream>>>(wvb, xb, bv, vT, 1024, 4096, 1024);

    k_rope<<<8192, 256, 0, stream>>>(qb, cosT, sinT);
    k_rope<<<8192, 256, 0, stream>>>(kb, cosT, sinT);

    dim3 g3(S_LEN / 64, BATCH * NHEAD);          // (32, 32)
    k_attn<<<g3, 256, 0, stream>>>(qb, kb, vT, ob);

    k_gemm<2, float><<<g1, 256, 0, stream>>>(ob, wob, bo, (float*)d_out, 4096, 1024, 1024);
}

// Round 3
// 253.338 us; speedup vs baseline: 1.4706x; 1.4706x over previous
//
#include <hip/hip_runtime.h>
#include <stdint.h>

#define S_LEN 2048
#define BATCH 2
#define EMB   1024
#define NHEAD 16
#define HDIM  64

typedef __bf16 bf8   __attribute__((ext_vector_type(8)));
typedef float  f32x4 __attribute__((ext_vector_type(4)));
typedef float  f32x16 __attribute__((ext_vector_type(16)));

__device__ __forceinline__ unsigned short f2bf(float f) {
    unsigned u = __builtin_bit_cast(unsigned, f);
    u += 0x7fffu + ((u >> 16) & 1u);          // round-to-nearest-even
    return (unsigned short)(u >> 16);
}
__device__ __forceinline__ float bf2f(unsigned short h) {
    unsigned u = ((unsigned)h) << 16;
    return __builtin_bit_cast(float, u);
}

__device__ __forceinline__ void gl_lds16(const unsigned short* g, unsigned short* l) {
    __builtin_amdgcn_global_load_lds(
        (__attribute__((address_space(1))) void*)(void*)g,
        (__attribute__((address_space(3))) void*)(void*)l, 16, 0, 0);
}

// ---------------- rope tables: cos/sin [S][64] fp32 ----------------
__global__ void k_tables(float* __restrict__ cosT, float* __restrict__ sinT) {
    int idx = blockIdx.x * 256 + threadIdx.x;   // 2048*64 = 131072
    int s = idx >> 6, d = idx & 63, j = d & 31;
    float inv = exp2f(-13.28771237954945f * ((float)j * (1.0f / 32.0f))); // 10000^(-j/32)
    float ang = (float)s * inv;
    cosT[idx] = cosf(ang);
    sinT[idx] = sinf(ang);
}

// ---------------- cast query [S,B,E] f32 -> xb [B,S,E] bf16 ----------------
__global__ void k_cast_x(const float* __restrict__ x, unsigned short* __restrict__ xb) {
    int id = blockIdx.x * 256 + threadIdx.x;    // 1048576 (4 elems each)
    int b = id >> 19, rem = id & 524287;
    int s = rem >> 8, e4 = (rem & 255) << 2;
    float4 v = *(const float4*)&x[((size_t)(s * BATCH + b)) * EMB + e4];
    ushort4 o;
    o.x = f2bf(v.x); o.y = f2bf(v.y); o.z = f2bf(v.z); o.w = f2bf(v.w);
    *(ushort4*)&xb[((size_t)(b * S_LEN + s)) * EMB + e4] = o;
}

// ---------------- all four weight casts in one launch ----------------
__global__ void k_castW(const float* __restrict__ w0, const float* __restrict__ w1,
                        const float* __restrict__ w2, const float* __restrict__ w3,
                        unsigned short* __restrict__ o0, unsigned short* __restrict__ o1,
                        unsigned short* __restrict__ o2, unsigned short* __restrict__ o3) {
    int id = blockIdx.x * 256 + threadIdx.x;    // 4 segments * 262144
    int seg = id >> 18, r = id & 262143;
    const float* s = seg == 0 ? w0 : seg == 1 ? w1 : seg == 2 ? w2 : w3;
    unsigned short* o = seg == 0 ? o0 : seg == 1 ? o1 : seg == 2 ? o2 : o3;
    float4 v = *(const float4*)&s[(size_t)r * 4];
    ushort4 u;
    u.x = f2bf(v.x); u.y = f2bf(v.y); u.z = f2bf(v.z); u.w = f2bf(v.w);
    *(ushort4*)&o[(size_t)r * 4] = u;
}

// ---------------- RoPE in-place on [B,S,E] bf16 buffer ----------------
// QSCALE: fold 0.125 (1/sqrt(hd)) * log2(e) into q so attention works in exp2 domain.
template<int QSCALE>
__global__ void k_rope(unsigned short* __restrict__ buf,
                       const float* __restrict__ cosT, const float* __restrict__ sinT) {
    int id = blockIdx.x * 256 + threadIdx.x;    // B*S*H*32 = 2097152
    int d = id & 31;
    int h = (id >> 5) & 15;
    int s = (id >> 9) & 2047;
    int b = id >> 20;
    size_t base = ((size_t)(b * S_LEN + s)) * EMB + h * HDIM + d;
    float x1 = bf2f(buf[base]);
    float x2 = bf2f(buf[base + 32]);
    float f  = QSCALE ? 0.125f * 1.44269504089f : 1.0f;
    float c  = cosT[s * 64 + d] * f;
    float sn = sinT[s * 64 + d] * f;
    buf[base]      = f2bf(x1 * c - x2 * sn);
    buf[base + 32] = f2bf(x2 * c + x1 * sn);
}

// ---------------- GEMM: C[M][N] = A[M][K] * B[N][K]^T + bias ----------------
// EPI 0: C row-major [M][N] bf16, bias over cols (q/k projections)
// EPI 1: C row-major [M][N] bf16, bias over rows (vT = W*X^T, bias per f-row)
// EPI 2: fp32 output, bias over cols, rows remapped m=b*2048+s -> s*2+b (d_out)
template<int EPI, typename OutT>
__global__ void __launch_bounds__(256) k_gemm(
    const unsigned short* __restrict__ A,
    const unsigned short* __restrict__ B,
    const float* __restrict__ bias,
    OutT* __restrict__ C,
    int M, int N, int K)
{
    __shared__ __align__(16) unsigned short As[128 * 32];
    __shared__ __align__(16) unsigned short Bs[128 * 32];
    const int tid  = threadIdx.x;
    const int lane = tid & 63;
    const int wid  = tid >> 6;
    const int wm = wid >> 1, wn = wid & 1;
    const int l15 = lane & 15, lh = lane >> 4;
    const int tm0 = blockIdx.y * 128, tn0 = blockIdx.x * 128;

    f32x4 acc[4][4] = {};

    for (int k0 = 0; k0 < K; k0 += 32) {
        __syncthreads();
#pragma unroll
        for (int rnd = 0; rnd < 2; ++rnd) {
            int cbase = wid * 64 + rnd * 256;          // wave-uniform chunk base
            int c = cbase + lane;
            int row = c >> 2, co = (c & 3) * 8;
            gl_lds16(A + (size_t)(tm0 + row) * K + k0 + co, &As[cbase * 8]);
            gl_lds16(B + (size_t)(tn0 + row) * K + k0 + co, &Bs[cbase * 8]);
        }
        __syncthreads();
        bf8 a[4], b[4];
#pragma unroll
        for (int i = 0; i < 4; ++i) {
            a[i] = *(const bf8*)&As[(wm * 64 + i * 16 + l15) * 32 + lh * 8];
            b[i] = *(const bf8*)&Bs[(wn * 64 + i * 16 + l15) * 32 + lh * 8];
        }
#pragma unroll
        for (int i = 0; i < 4; ++i)
#pragma unroll
            for (int j = 0; j < 4; ++j)
                acc[i][j] = __builtin_amdgcn_mfma_f32_16x16x32_bf16(a[i], b[j], acc[i][j], 0, 0, 0);
    }

#pragma unroll
    for (int i = 0; i < 4; ++i) {
        const int rowb = tm0 + wm * 64 + i * 16 + lh * 4;
#pragma unroll
        for (int j = 0; j < 4; ++j) {
            const int col = tn0 + wn * 64 + j * 16 + l15;
#pragma unroll
            for (int r = 0; r < 4; ++r) {
                float v = acc[i][j][r];
                int row = rowb + r;
                if (EPI == 0) {
                    v += bias[col];
                    C[(size_t)row * N + col] = (OutT)f2bf(v);
                } else if (EPI == 1) {
                    v += bias[row];
                    C[(size_t)row * N + col] = (OutT)f2bf(v);
                } else {
                    v += bias[col];
                    int bb = row >> 11, ss = row & 2047;
                    ((float*)C)[(size_t)(ss * BATCH + bb) * N + col] = v;
                }
            }
        }
    }
}

// ---------------- flash attention, swapped-QK 32x32 structure ----------------
// grid: (S/128, B*H). 4 waves/block, each wave owns QBLK=32 q rows; KVBLK=32.
// qb: [B,S,E] bf16 (rope'd, pre-scaled by 0.125*log2e). kb: [B,S,E] bf16 (rope'd).
// vT: [E][B*S] bf16 (v transposed, bias included). ob: [B,S,E] bf16.
// S_t = mfma(K,Q): lane holds S[kv = (r&3)+8*(r>>2)+4*hi][q = lane&31] -> softmax
// nearly lane-local. Online softmax in log2 domain, defer-max THR = 8*log2e.
__global__ void __launch_bounds__(256) k_attn2(
    const unsigned short* __restrict__ qb,
    const unsigned short* __restrict__ kb,
    const unsigned short* __restrict__ vT,
    unsigned short* __restrict__ ob)
{
    __shared__ float bl[4][32];
    const int tid = threadIdx.x, lane = tid & 63, wid = tid >> 6;
    const int l31 = lane & 31, hi = lane >> 5;
    const int b = blockIdx.y >> 4, h = blockIdx.y & 15;
    const int q0 = blockIdx.x * 128 + wid * 32;

    const unsigned short* qrow = qb + ((size_t)(b * S_LEN + q0 + l31)) * EMB + h * HDIM;
    bf8 qf[4];
#pragma unroll
    for (int c = 0; c < 4; ++c)
        qf[c] = *(const bf8*)(qrow + c * 16 + hi * 8);

    float m_run = 0.f, l_run = 0.f;
    f32x16 oacc0 = {}, oacc1 = {};

    const unsigned short* vbase =
        vT + ((size_t)(h * HDIM + l31)) * (S_LEN * BATCH) + b * S_LEN + hi * 8;

    for (int j0 = 0; j0 < S_LEN; j0 += 32) {
        const unsigned short* krow =
            kb + ((size_t)(b * S_LEN + j0 + l31)) * EMB + h * HDIM;
        f32x16 st = {};
#pragma unroll
        for (int c = 0; c < 4; ++c) {
            bf8 kf = *(const bf8*)(krow + c * 16 + hi * 8);
            st = __builtin_amdgcn_mfma_f32_32x32x16_bf16(kf, qf[c], st, 0, 0, 0);
        }
        // ---- online softmax, log2 domain; lane owns q = l31 ----
        float pmax = st[0];
#pragma unroll
        for (int r = 1; r < 16; ++r) pmax = fmaxf(pmax, st[r]);
        pmax = fmaxf(pmax, __shfl_xor(pmax, 32));
        if (!__all(pmax - m_run <= 11.54f)) {       // rare rescale path
            float mnew = fmaxf(m_run, pmax);
            float corr = exp2f(m_run - mnew);
            l_run *= corr;
            m_run = mnew;
            if (hi == 0) bl[wid][l31] = corr;
            asm volatile("s_waitcnt lgkmcnt(0)" ::: "memory");
#pragma unroll
            for (int r = 0; r < 16; ++r) {
                float c2 = bl[wid][(r & 3) + 8 * (r >> 2) + 4 * hi];
                oacc0[r] *= c2;
                oacc1[r] *= c2;
            }
        }
        float p[16], psum = 0.f;
#pragma unroll
        for (int r = 0; r < 16; ++r) { p[r] = exp2f(st[r] - m_run); psum += p[r]; }
        psum += __shfl_xor(psum, 32);
        l_run += psum;

        // ---- pack P to bf16 and half-exchange into PV A-fragments ----
        unsigned c01 = ((unsigned)f2bf(p[1])  << 16) | f2bf(p[0]);
        unsigned c23 = ((unsigned)f2bf(p[3])  << 16) | f2bf(p[2]);
        unsigned c45 = ((unsigned)f2bf(p[5])  << 16) | f2bf(p[4]);
        unsigned c67 = ((unsigned)f2bf(p[7])  << 16) | f2bf(p[6]);
        unsigned c89 = ((unsigned)f2bf(p[9])  << 16) | f2bf(p[8]);
        unsigned cab = ((unsigned)f2bf(p[11]) << 16) | f2bf(p[10]);
        unsigned ccd = ((unsigned)f2bf(p[13]) << 16) | f2bf(p[12]);
        unsigned cef = ((unsigned)f2bf(p[15]) << 16) | f2bf(p[14]);
        unsigned rA = (unsigned)__shfl_xor((int)(hi ? c01 : c45), 32);
        unsigned rB = (unsigned)__shfl_xor((int)(hi ? c23 : c67), 32);
        unsigned rC = (unsigned)__shfl_xor((int)(hi ? c89 : ccd), 32);
        unsigned rD = (unsigned)__shfl_xor((int)(hi ? cab : cef), 32);
        uint4 f0u = hi ? uint4{rA, rB, c45, c67} : uint4{c01, c23, rA, rB};
        uint4 f1u = hi ? uint4{rC, rD, ccd, cef} : uint4{c89, cab, rC, rD};
        bf8 pf0 = __builtin_bit_cast(bf8, f0u);
        bf8 pf1 = __builtin_bit_cast(bf8, f1u);

        // ---- PV: O[q][dv] += P * V ----
        const unsigned short* vr0 = vbase + j0;
        const unsigned short* vr1 = vbase + (size_t)32 * (S_LEN * BATCH) + j0;
        bf8 va0 = *(const bf8*)(vr0);
        bf8 va1 = *(const bf8*)(vr0 + 16);
        bf8 vb0 = *(const bf8*)(vr1);
        bf8 vb1 = *(const bf8*)(vr1 + 16);
        oacc0 = __builtin_amdgcn_mfma_f32_32x32x16_bf16(pf0, va0, oacc0, 0, 0, 0);
        oacc0 = __builtin_amdgcn_mfma_f32_32x32x16_bf16(pf1, va1, oacc0, 0, 0, 0);
        oacc1 = __builtin_amdgcn_mfma_f32_32x32x16_bf16(pf0, vb0, oacc1, 0, 0, 0);
        oacc1 = __builtin_amdgcn_mfma_f32_32x32x16_bf16(pf1, vb1, oacc1, 0, 0, 0);
    }

    // ---- epilogue: broadcast denominators, normalize, store ----
    if (hi == 0) bl[wid][l31] = l_run;
    asm volatile("s_waitcnt lgkmcnt(0)" ::: "memory");
#pragma unroll
    for (int r = 0; r < 16; ++r) {
        int q = (r & 3) + 8 * (r >> 2) + 4 * hi;
        float linv = 1.0f / bl[wid][q];
        size_t base = ((size_t)(b * S_LEN + q0 + q)) * EMB + h * HDIM + l31;
        ob[base]      = f2bf(oacc0[r] * linv);
        ob[base + 32] = f2bf(oacc1[r] * linv);
    }
}

extern "C" void kernel_launch(void* const* d_in, const int* in_sizes, int n_in,
                              void* d_out, int out_size, void* d_ws, size_t ws_size,
                              hipStream_t stream)
{
    (void)in_sizes; (void)n_in; (void)out_size; (void)ws_size;
    const float* query = (const float*)d_in[0];
    const float* wq = (const float*)d_in[1];
    const float* bq = (const float*)d_in[2];
    const float* wk = (const float*)d_in[3];
    const float* bk = (const float*)d_in[4];
    const float* wv = (const float*)d_in[5];
    const float* bv = (const float*)d_in[6];
    const float* wo = (const float*)d_in[7];
    const float* bo = (const float*)d_in[8];

    char* ws = (char*)d_ws;
    float*          cosT = (float*)(ws + 0);
    float*          sinT = (float*)(ws + (512 << 10));
    unsigned short* xb   = (unsigned short*)(ws + (1  << 20));  // [B,S,E]   8 MB
    unsigned short* wqb  = (unsigned short*)(ws + (9  << 20));  // [E,E]     2 MB
    unsigned short* wkb  = (unsigned short*)(ws + (11 << 20));
    unsigned short* wvb  = (unsigned short*)(ws + (13 << 20));
    unsigned short* wob  = (unsigned short*)(ws + (15 << 20));
    unsigned short* qb   = (unsigned short*)(ws + (17 << 20));  // [B,S,E]
    unsigned short* kb   = (unsigned short*)(ws + (25 << 20));
    unsigned short* vT   = (unsigned short*)(ws + (33 << 20));  // [E][B*S]
    unsigned short* ob   = (unsigned short*)(ws + (41 << 20));  // [B,S,E]

    k_tables<<<512, 256, 0, stream>>>(cosT, sinT);
    k_cast_x<<<4096, 256, 0, stream>>>(query, xb);
    k_castW<<<4096, 256, 0, stream>>>(wq, wk, wv, wo, wqb, wkb, wvb, wob);

    dim3 g1(EMB / 128, (S_LEN * BATCH) / 128);   // (8, 32)
    k_gemm<0, unsigned short><<<g1, 256, 0, stream>>>(xb, wqb, bq, qb, 4096, 1024, 1024);
    k_gemm<0, unsigned short><<<g1, 256, 0, stream>>>(xb, wkb, bk, kb, 4096, 1024, 1024);
    dim3 g2((S_LEN * BATCH) / 128, EMB / 128);   // (32, 8)
    k_gemm<1, unsigned short><<<g2, 256, 0, stream>>>(wvb, xb, bv, vT, 1024, 4096, 1024);

    k_rope<1><<<8192, 256, 0, stream>>>(qb, cosT, sinT);
    k_rope<0><<<8192, 256, 0, stream>>>(kb, cosT, sinT);

    dim3 g3(S_LEN / 128, BATCH * NHEAD);         // (16, 32)
    k_attn2<<<g3, 256, 0, stream>>>(qb, kb, vT, ob);

    k_gemm<2, float><<<g1, 256, 0, stream>>>(ob, wob, bo, (float*)d_out, 4096, 1024, 1024);
}

// Round 4
// 252.871 us; speedup vs baseline: 1.4734x; 1.0018x over previous
//
#include <hip/hip_runtime.h>
#include <stdint.h>

#define S_LEN 2048
#define BATCH 2
#define EMB   1024
#define NHEAD 16
#define HDIM  64

typedef __bf16 bf8   __attribute__((ext_vector_type(8)));
typedef float  f32x4 __attribute__((ext_vector_type(4)));
typedef float  f32x16 __attribute__((ext_vector_type(16)));

__device__ __forceinline__ unsigned short f2bf(float f) {
    unsigned u = __builtin_bit_cast(unsigned, f);
    u += 0x7fffu + ((u >> 16) & 1u);          // round-to-nearest-even
    return (unsigned short)(u >> 16);
}
__device__ __forceinline__ float bf2f(unsigned short h) {
    unsigned u = ((unsigned)h) << 16;
    return __builtin_bit_cast(float, u);
}

__device__ __forceinline__ void gl_lds16(const unsigned short* g, unsigned short* l) {
    __builtin_amdgcn_global_load_lds(
        (__attribute__((address_space(1))) void*)(void*)g,
        (__attribute__((address_space(3))) void*)(void*)l, 16, 0, 0);
}

// ---------------- rope tables: cos/sin [S][64] fp32 ----------------
__global__ void k_tables(float* __restrict__ cosT, float* __restrict__ sinT) {
    int idx = blockIdx.x * 256 + threadIdx.x;   // 2048*64 = 131072
    int s = idx >> 6, d = idx & 63, j = d & 31;
    float inv = exp2f(-13.28771237954945f * ((float)j * (1.0f / 32.0f))); // 10000^(-j/32)
    float ang = (float)s * inv;
    cosT[idx] = cosf(ang);
    sinT[idx] = sinf(ang);
}

// ---------------- cast query [S,B,E] f32 -> xb [B,S,E] bf16 ----------------
__global__ void k_cast_x(const float* __restrict__ x, unsigned short* __restrict__ xb) {
    int id = blockIdx.x * 256 + threadIdx.x;    // 1048576 (4 elems each)
    int b = id >> 19, rem = id & 524287;
    int s = rem >> 8, e4 = (rem & 255) << 2;
    float4 v = *(const float4*)&x[((size_t)(s * BATCH + b)) * EMB + e4];
    ushort4 o;
    o.x = f2bf(v.x); o.y = f2bf(v.y); o.z = f2bf(v.z); o.w = f2bf(v.w);
    *(ushort4*)&xb[((size_t)(b * S_LEN + s)) * EMB + e4] = o;
}

// ---------------- all four weight casts in one launch ----------------
__global__ void k_castW(const float* __restrict__ w0, const float* __restrict__ w1,
                        const float* __restrict__ w2, const float* __restrict__ w3,
                        unsigned short* __restrict__ o0, unsigned short* __restrict__ o1,
                        unsigned short* __restrict__ o2, unsigned short* __restrict__ o3) {
    int id = blockIdx.x * 256 + threadIdx.x;    // 4 segments * 262144
    int seg = id >> 18, r = id & 262143;
    const float* s = seg == 0 ? w0 : seg == 1 ? w1 : seg == 2 ? w2 : w3;
    unsigned short* o = seg == 0 ? o0 : seg == 1 ? o1 : seg == 2 ? o2 : o3;
    float4 v = *(const float4*)&s[(size_t)r * 4];
    ushort4 u;
    u.x = f2bf(v.x); u.y = f2bf(v.y); u.z = f2bf(v.z); u.w = f2bf(v.w);
    *(ushort4*)&o[(size_t)r * 4] = u;
}

// ---------------- RoPE in-place on q and k buffers, one launch ----------------
// q gets the extra 0.125*log2e factor folded in (exp2-domain softmax).
__global__ void k_rope2(unsigned short* __restrict__ qbuf, unsigned short* __restrict__ kbuf,
                        const float* __restrict__ cosT, const float* __restrict__ sinT) {
    int id = blockIdx.x * 256 + threadIdx.x;    // 2 * B*S*H*32 = 4194304
    int which = id >> 21;
    int r = id & 2097151;
    unsigned short* buf = which ? kbuf : qbuf;
    float f = which ? 1.0f : 0.125f * 1.44269504089f;
    int d = r & 31;
    int h = (r >> 5) & 15;
    int s = (r >> 9) & 2047;
    int b = r >> 20;
    size_t base = ((size_t)(b * S_LEN + s)) * EMB + h * HDIM + d;
    float x1 = bf2f(buf[base]);
    float x2 = bf2f(buf[base + 32]);
    float c  = cosT[s * 64 + d] * f;
    float sn = sinT[s * 64 + d] * f;
    buf[base]      = f2bf(x1 * c - x2 * sn);
    buf[base + 32] = f2bf(x2 * c + x1 * sn);
}

// ---------------- GEMM: C[M][N] = A[M][K] * B[N][K]^T + bias ----------------
// EPI 0: C row-major [M][N] bf16, bias over cols (q/k projections)
// EPI 1: C row-major [M][N] bf16, bias over rows (vT = W*X^T, bias per f-row)
// EPI 2: fp32 output, bias over cols, rows remapped m=b*2048+s -> s*2+b (d_out)
template<int EPI, typename OutT>
__global__ void __launch_bounds__(256) k_gemm(
    const unsigned short* __restrict__ A,
    const unsigned short* __restrict__ B,
    const float* __restrict__ bias,
    OutT* __restrict__ C,
    int M, int N, int K)
{
    __shared__ __align__(16) unsigned short As[128 * 32];
    __shared__ __align__(16) unsigned short Bs[128 * 32];
    const int tid  = threadIdx.x;
    const int lane = tid & 63;
    const int wid  = tid >> 6;
    const int wm = wid >> 1, wn = wid & 1;
    const int l15 = lane & 15, lh = lane >> 4;
    const int tm0 = blockIdx.y * 128, tn0 = blockIdx.x * 128;

    f32x4 acc[4][4] = {};

    for (int k0 = 0; k0 < K; k0 += 32) {
        __syncthreads();
#pragma unroll
        for (int rnd = 0; rnd < 2; ++rnd) {
            int cbase = wid * 64 + rnd * 256;          // wave-uniform chunk base
            int c = cbase + lane;
            int row = c >> 2, co = (c & 3) * 8;
            gl_lds16(A + (size_t)(tm0 + row) * K + k0 + co, &As[cbase * 8]);
            gl_lds16(B + (size_t)(tn0 + row) * K + k0 + co, &Bs[cbase * 8]);
        }
        __syncthreads();
        bf8 a[4], b[4];
#pragma unroll
        for (int i = 0; i < 4; ++i) {
            a[i] = *(const bf8*)&As[(wm * 64 + i * 16 + l15) * 32 + lh * 8];
            b[i] = *(const bf8*)&Bs[(wn * 64 + i * 16 + l15) * 32 + lh * 8];
        }
#pragma unroll
        for (int i = 0; i < 4; ++i)
#pragma unroll
            for (int j = 0; j < 4; ++j)
                acc[i][j] = __builtin_amdgcn_mfma_f32_16x16x32_bf16(a[i], b[j], acc[i][j], 0, 0, 0);
    }

#pragma unroll
    for (int i = 0; i < 4; ++i) {
        const int rowb = tm0 + wm * 64 + i * 16 + lh * 4;
#pragma unroll
        for (int j = 0; j < 4; ++j) {
            const int col = tn0 + wn * 64 + j * 16 + l15;
#pragma unroll
            for (int r = 0; r < 4; ++r) {
                float v = acc[i][j][r];
                int row = rowb + r;
                if (EPI == 0) {
                    v += bias[col];
                    C[(size_t)row * N + col] = (OutT)f2bf(v);
                } else if (EPI == 1) {
                    v += bias[row];
                    C[(size_t)row * N + col] = (OutT)f2bf(v);
                } else {
                    v += bias[col];
                    int bb = row >> 11, ss = row & 2047;
                    ((float*)C)[(size_t)(ss * BATCH + bb) * N + col] = v;
                }
            }
        }
    }
}

// ---------------- flash attention, swapped-QK 32x32, KVBLK=64, K-prefetch ----------------
// grid: (S/128, B*H). 4 waves/block, each wave owns QBLK=32 q rows.
// qb: [B,S,E] bf16 (rope'd, pre-scaled by 0.125*log2e). kb: [B,S,E] bf16 (rope'd).
// vT: [E][B*S] bf16 (v transposed, bias included). ob: [B,S,E] bf16.
// S_t = mfma(K,Q): lane holds S[kv=(r&3)+8*(r>>2)+4*hi][q=lane&31].
__global__ void __launch_bounds__(256) k_attn3(
    const unsigned short* __restrict__ qb,
    const unsigned short* __restrict__ kb,
    const unsigned short* __restrict__ vT,
    unsigned short* __restrict__ ob)
{
    __shared__ float bl[4][32];
    const int tid = threadIdx.x, lane = tid & 63, wid = tid >> 6;
    const int l31 = lane & 31, hi = lane >> 5;
    const int b = blockIdx.y >> 4, h = blockIdx.y & 15;
    const int q0 = blockIdx.x * 128 + wid * 32;

    const unsigned short* qrow = qb + ((size_t)(b * S_LEN + q0 + l31)) * EMB + h * HDIM + hi * 8;
    bf8 qf[4];
#pragma unroll
    for (int c = 0; c < 4; ++c) qf[c] = *(const bf8*)(qrow + c * 16);

    const unsigned short* kbase = kb + ((size_t)(b * S_LEN + l31)) * EMB + h * HDIM + hi * 8;
    const unsigned short* vb0 = vT + ((size_t)(h * HDIM + l31)) * (S_LEN * BATCH) + b * S_LEN + hi * 8;
    const unsigned short* vb1 = vb0 + (size_t)32 * (S_LEN * BATCH);

    float m_run = 0.f, l_run = 0.f;
    f32x16 oacc0 = {}, oacc1 = {};

    bf8 kr0[8], kr1[8];   // double-buffered K fragments; [0..3]=chunk A, [4..7]=chunk B

    auto loadK = [&](int j, bf8 (&kr)[8]) {
        const unsigned short* pa = kbase + (size_t)j * EMB;
        const unsigned short* pb = kbase + (size_t)(j + 32) * EMB;
#pragma unroll
        for (int c = 0; c < 4; ++c) {
            kr[c]     = *(const bf8*)(pa + c * 16);
            kr[4 + c] = *(const bf8*)(pb + c * 16);
        }
    };

    auto pack2 = [](float lo, float hh) -> unsigned {
        unsigned short a  = __builtin_bit_cast(unsigned short, (__bf16)lo);
        unsigned short bb = __builtin_bit_cast(unsigned short, (__bf16)hh);
        return ((unsigned)bb << 16) | a;
    };

    loadK(0, kr0);

    auto body = [&](bf8 (&ck)[8], bf8 (&nk)[8], int j0, int jn) {
        // prefetch next K chunk-pair (cross-iteration latency hiding)
        loadK(jn, nk);
        // V loads for current chunk; consumed after QK+softmax (~500 cyc of cover)
        bf8 v0[4], v1[4];
#pragma unroll
        for (int c = 0; c < 4; ++c) {
            v0[c] = *(const bf8*)(vb0 + j0 + c * 16);
            v1[c] = *(const bf8*)(vb1 + j0 + c * 16);
        }
        // QK^T: two independent accumulator chains
        f32x16 stA = {}, stB = {};
#pragma unroll
        for (int c = 0; c < 4; ++c) {
            stA = __builtin_amdgcn_mfma_f32_32x32x16_bf16(ck[c],     qf[c], stA, 0, 0, 0);
            stB = __builtin_amdgcn_mfma_f32_32x32x16_bf16(ck[4 + c], qf[c], stB, 0, 0, 0);
        }
        // ---- max, balanced tree ----
        float mx[8];
#pragma unroll
        for (int i = 0; i < 8; ++i)
            mx[i] = fmaxf(fmaxf(stA[i], stA[i + 8]), fmaxf(stB[i], stB[i + 8]));
        float t0 = fmaxf(mx[0], mx[4]), t1 = fmaxf(mx[1], mx[5]);
        float t2 = fmaxf(mx[2], mx[6]), t3 = fmaxf(mx[3], mx[7]);
        float pmax = fmaxf(fmaxf(t0, t1), fmaxf(t2, t3));
        pmax = fmaxf(pmax, __shfl_xor(pmax, 32));
        if (!__all(pmax - m_run <= 11.54f)) {       // rare rescale path (defer-max)
            float mnew = fmaxf(m_run, pmax);
            float corr = exp2f(m_run - mnew);
            l_run *= corr;
            m_run = mnew;
            if (hi == 0) bl[wid][l31] = corr;
            asm volatile("s_waitcnt lgkmcnt(0)" ::: "memory");
#pragma unroll
            for (int r = 0; r < 16; ++r) {
                float c2 = bl[wid][(r & 3) + 8 * (r >> 2) + 4 * hi];
                oacc0[r] *= c2;
                oacc1[r] *= c2;
            }
        }
        // ---- chunk A: exp2, sum tree, pack ----
        float pA[16];
#pragma unroll
        for (int r = 0; r < 16; ++r) pA[r] = exp2f(stA[r] - m_run);
        float sA = ((pA[0] + pA[1]) + (pA[2] + pA[3])) + ((pA[4] + pA[5]) + (pA[6] + pA[7]));
        float sA2 = ((pA[8] + pA[9]) + (pA[10] + pA[11])) + ((pA[12] + pA[13]) + (pA[14] + pA[15]));
        unsigned a01 = pack2(pA[0], pA[1]),   a23 = pack2(pA[2], pA[3]);
        unsigned a45 = pack2(pA[4], pA[5]),   a67 = pack2(pA[6], pA[7]);
        unsigned a89 = pack2(pA[8], pA[9]),   aab = pack2(pA[10], pA[11]);
        unsigned acd = pack2(pA[12], pA[13]), aef = pack2(pA[14], pA[15]);
        unsigned rA = (unsigned)__shfl_xor((int)(hi ? a01 : a45), 32);
        unsigned rB = (unsigned)__shfl_xor((int)(hi ? a23 : a67), 32);
        unsigned rC = (unsigned)__shfl_xor((int)(hi ? a89 : acd), 32);
        unsigned rD = (unsigned)__shfl_xor((int)(hi ? aab : aef), 32);
        uint4 u0 = hi ? uint4{rA, rB, a45, a67} : uint4{a01, a23, rA, rB};
        uint4 u1 = hi ? uint4{rC, rD, acd, aef} : uint4{a89, aab, rC, rD};
        bf8 pf0A = __builtin_bit_cast(bf8, u0);
        bf8 pf1A = __builtin_bit_cast(bf8, u1);
        // ---- chunk B ----
        float pB[16];
#pragma unroll
        for (int r = 0; r < 16; ++r) pB[r] = exp2f(stB[r] - m_run);
        float sB = ((pB[0] + pB[1]) + (pB[2] + pB[3])) + ((pB[4] + pB[5]) + (pB[6] + pB[7]));
        float sB2 = ((pB[8] + pB[9]) + (pB[10] + pB[11])) + ((pB[12] + pB[13]) + (pB[14] + pB[15]));
        unsigned b01 = pack2(pB[0], pB[1]),   b23 = pack2(pB[2], pB[3]);
        unsigned b45 = pack2(pB[4], pB[5]),   b67 = pack2(pB[6], pB[7]);
        unsigned b89 = pack2(pB[8], pB[9]),   bab = pack2(pB[10], pB[11]);
        unsigned bcd = pack2(pB[12], pB[13]), bef = pack2(pB[14], pB[15]);
        unsigned sA_ = (unsigned)__shfl_xor((int)(hi ? b01 : b45), 32);
        unsigned sB_ = (unsigned)__shfl_xor((int)(hi ? b23 : b67), 32);
        unsigned sC_ = (unsigned)__shfl_xor((int)(hi ? b89 : bcd), 32);
        unsigned sD_ = (unsigned)__shfl_xor((int)(hi ? bab : bef), 32);
        uint4 w0 = hi ? uint4{sA_, sB_, b45, b67} : uint4{b01, b23, sA_, sB_};
        uint4 w1 = hi ? uint4{sC_, sD_, bcd, bef} : uint4{b89, bab, sC_, sD_};
        bf8 pf0B = __builtin_bit_cast(bf8, w0);
        bf8 pf1B = __builtin_bit_cast(bf8, w1);

        float psum = (sA + sA2) + (sB + sB2);
        psum += __shfl_xor(psum, 32);
        l_run += psum;

        // ---- PV: two independent accumulator chains ----
        oacc0 = __builtin_amdgcn_mfma_f32_32x32x16_bf16(pf0A, v0[0], oacc0, 0, 0, 0);
        oacc1 = __builtin_amdgcn_mfma_f32_32x32x16_bf16(pf0A, v1[0], oacc1, 0, 0, 0);
        oacc0 = __builtin_amdgcn_mfma_f32_32x32x16_bf16(pf1A, v0[1], oacc0, 0, 0, 0);
        oacc1 = __builtin_amdgcn_mfma_f32_32x32x16_bf16(pf1A, v1[1], oacc1, 0, 0, 0);
        oacc0 = __builtin_amdgcn_mfma_f32_32x32x16_bf16(pf0B, v0[2], oacc0, 0, 0, 0);
        oacc1 = __builtin_amdgcn_mfma_f32_32x32x16_bf16(pf0B, v1[2], oacc1, 0, 0, 0);
        oacc0 = __builtin_amdgcn_mfma_f32_32x32x16_bf16(pf1B, v0[3], oacc0, 0, 0, 0);
        oacc1 = __builtin_amdgcn_mfma_f32_32x32x16_bf16(pf1B, v1[3], oacc1, 0, 0, 0);
    };

    for (int j0 = 0; j0 < S_LEN; j0 += 128) {
        body(kr0, kr1, j0,      j0 + 64);
        body(kr1, kr0, j0 + 64, (j0 + 128) & (S_LEN - 1));
    }

    // ---- epilogue: broadcast denominators, normalize, store ----
    if (hi == 0) bl[wid][l31] = l_run;
    asm volatile("s_waitcnt lgkmcnt(0)" ::: "memory");
#pragma unroll
    for (int r = 0; r < 16; ++r) {
        int q = (r & 3) + 8 * (r >> 2) + 4 * hi;
        float linv = 1.0f / bl[wid][q];
        size_t base = ((size_t)(b * S_LEN + q0 + q)) * EMB + h * HDIM + l31;
        ob[base]      = f2bf(oacc0[r] * linv);
        ob[base + 32] = f2bf(oacc1[r] * linv);
    }
}

extern "C" void kernel_launch(void* const* d_in, const int* in_sizes, int n_in,
                              void* d_out, int out_size, void* d_ws, size_t ws_size,
                              hipStream_t stream)
{
    (void)in_sizes; (void)n_in; (void)out_size; (void)ws_size;
    const float* query = (const float*)d_in[0];
    const float* wq = (const float*)d_in[1];
    const float* bq = (const float*)d_in[2];
    const float* wk = (const float*)d_in[3];
    const float* bk = (const float*)d_in[4];
    const float* wv = (const float*)d_in[5];
    const float* bv = (const float*)d_in[6];
    const float* wo = (const float*)d_in[7];
    const float* bo = (const float*)d_in[8];

    char* ws = (char*)d_ws;
    float*          cosT = (float*)(ws + 0);
    float*          sinT = (float*)(ws + (512 << 10));
    unsigned short* xb   = (unsigned short*)(ws + (1  << 20));  // [B,S,E]   8 MB
    unsigned short* wqb  = (unsigned short*)(ws + (9  << 20));  // [E,E]     2 MB
    unsigned short* wkb  = (unsigned short*)(ws + (11 << 20));
    unsigned short* wvb  = (unsigned short*)(ws + (13 << 20));
    unsigned short* wob  = (unsigned short*)(ws + (15 << 20));
    unsigned short* qb   = (unsigned short*)(ws + (17 << 20));  // [B,S,E]
    unsigned short* kb   = (unsigned short*)(ws + (25 << 20));
    unsigned short* vT   = (unsigned short*)(ws + (33 << 20));  // [E][B*S]
    unsigned short* ob   = (unsigned short*)(ws + (41 << 20));  // [B,S,E]

    k_tables<<<512, 256, 0, stream>>>(cosT, sinT);
    k_cast_x<<<4096, 256, 0, stream>>>(query, xb);
    k_castW<<<4096, 256, 0, stream>>>(wq, wk, wv, wo, wqb, wkb, wvb, wob);

    dim3 g1(EMB / 128, (S_LEN * BATCH) / 128);   // (8, 32)
    k_gemm<0, unsigned short><<<g1, 256, 0, stream>>>(xb, wqb, bq, qb, 4096, 1024, 1024);
    k_gemm<0, unsigned short><<<g1, 256, 0, stream>>>(xb, wkb, bk, kb, 4096, 1024, 1024);
    dim3 g2((S_LEN * BATCH) / 128, EMB / 128);   // (32, 8)
    k_gemm<1, unsigned short><<<g2, 256, 0, stream>>>(wvb, xb, bv, vT, 1024, 4096, 1024);

    k_rope2<<<16384, 256, 0, stream>>>(qb, kb, cosT, sinT);

    dim3 g3(S_LEN / 128, BATCH * NHEAD);         // (16, 32)
    k_attn3<<<g3, 256, 0, stream>>>(qb, kb, vT, ob);

    k_gemm<2, float><<<g1, 256, 0, stream>>>(ob, wob, bo, (float*)d_out, 4096, 1024, 1024);
}